// Round 11
// baseline (557.744 us; speedup 1.0000x reference)
//
#include <hip/hip_runtime.h>
#include <stdint.h>

static constexpr int HIN = 256, WIN = 256, HO = 254, WOUT = 254, NB = 8;
static constexpr int PLANE = HO * WOUT;       // 64516
static constexpr int PIX = NB * PLANE;        // 516128

// ---------------------------------------------------------------------------
// Two-phase structure. Phase 1 (conv_phase): thread = (pixel, 8-channel
// group); computes conv+bias (UNGATED, validated numerics) and writes the raw
// f32 bit patterns into the output buffer itself (out == 120 planes ==
// exactly the act tensor, ~248 MB ~ L3-resident). Phase 2 (select_phase):
// thread = pixel; reads back its 120 raw values (bit-exact round trip),
// applies the validated gate -> top-k -> keep chain per level entirely in
// registers, and overwrites out with the final selected values. Same-stream
// kernel ordering gives the RAW dependency; each (pixel,channel) entry is
// read/written by exactly one phase-2 thread, so no cross-thread hazards.
//
// Numerics (validated rounds 0-1, re-verified round 9 absmax 0.0): patch
// px[27] with px[c*9+dy*3+dx]; per atom a single f32 accumulator from 0,
// sequential __fmaf_rn in (ky,kx,c) order over wp = w + atom*27
// (t = c*9+ky*3+kx), bias added last as a separate __fadd_rn, gate applied
// after bias. Selection: jax top_k semantics — exactly K kept, boundary ties
// broken toward LOWEST index; m = K-th largest |act| with multiplicity via
// bitonic networks on the uint32 bit patterns of |act|.
// ---------------------------------------------------------------------------

// Ring connectivity: prev atom j feeds next atoms (2j..2j+3) mod a_next.
__device__ __forceinline__ uint64_t spread_pairs(uint64_t mask, int a_next) {
  uint64_t s = mask;
  s = (s | (s << 16)) & 0x0000FFFF0000FFFFull;
  s = (s | (s << 8))  & 0x00FF00FF00FF00FFull;
  s = (s | (s << 4))  & 0x0F0F0F0F0F0F0F0Full;
  s = (s | (s << 2))  & 0x3333333333333333ull;
  s = (s | (s << 1))  & 0x5555555555555555ull;
  uint64_t pair = s | (s << 1);
  uint64_t lim = (a_next >= 64) ? ~0ull : ((1ull << a_next) - 1ull);
  uint64_t rot = ((pair << 2) | (pair >> (a_next - 2))) & lim;
  return (pair | rot) & lim;
}

// Bitonic sort (descending) of K uint32 in registers; fully unrolled, static
// indices, pure v_min_u32/v_max_u32 (round-1/9 validated).
template<int K>
__device__ __forceinline__ void bsort_desc(uint32_t (&v)[K]) {
#pragma unroll
  for (int sz = 2; sz <= K; sz <<= 1) {
#pragma unroll
    for (int st = sz >> 1; st > 0; st >>= 1) {
#pragma unroll
      for (int i = 0; i < K; ++i) {
        int l = i ^ st;
        if (l > i) {
          uint32_t a = v[i], c = v[l];
          uint32_t mx = a > c ? a : c;
          uint32_t mn = a > c ? c : a;
          bool desc = ((i & sz) == 0);
          v[i] = desc ? mx : mn;
          v[l] = desc ? mn : mx;
        }
      }
    }
  }
}

__device__ __forceinline__ void bmerge16(uint32_t (&v)[16]) {
#pragma unroll
  for (int st = 8; st > 0; st >>= 1) {
#pragma unroll
    for (int i = 0; i < 16; ++i) {
      int l = i ^ st;
      if (l > i) {
        uint32_t a = v[i], c = v[l];
        v[i] = a > c ? a : c;
        v[l] = a > c ? c : a;
      }
    }
  }
}

// One atom's conv: validated (ky,kx,c)-ordered sequential FMA chain + bias.
__device__ __forceinline__ float conv_atom(const float (&px)[27],
                                           const float* __restrict__ wp,
                                           float bias) {
  float acc = 0.0f;
#pragma unroll
  for (int ky = 0; ky < 3; ++ky)
#pragma unroll
    for (int kx = 0; kx < 3; ++kx)
#pragma unroll
      for (int c = 0; c < 3; ++c) {
        int t = c * 9 + ky * 3 + kx;
        acc = __fmaf_rn(px[t], wp[t], acc);
      }
  return __fadd_rn(acc, bias);
}

// Keep + store + mask (validated ascending-j tie-break; quota in, msk out).
template<int N>
__device__ __forceinline__ uint64_t keep_store(const float (&act)[N], float m,
    int quota, char* __restrict__ outB, uint32_t tofs4, int ch0) {
  uint64_t msk = 0;
#pragma unroll
  for (int j = 0; j < N; ++j) {
    float aj = fabsf(act[j]);
    bool eq = (aj == m);
    bool keep = (aj > m) || (eq && quota > 0);
    quota -= eq ? 1 : 0;
    float v = keep ? act[j] : 0.0f;
    *(float*)(outB + (size_t)(ch0 + j) * PLANE * 4 + tofs4) = v;
    msk |= (v != 0.0f) ? (1ull << j) : 0ull;
  }
  return msk;
}

// ======================= phase 1: conv, 8 channels/thread ==================
// blockIdx.y = channel octet (15 total). Weights/bias uniform per block ->
// scalar loads. Live set ~45 VGPR -> 8 waves/SIMD; phase is write-BW-bound.
__global__ __launch_bounds__(256, 8)
void conv_phase(const float* __restrict__ x, const float* __restrict__ w,
                const float* __restrict__ b, float* __restrict__ out) {
  int p = blockIdx.x * blockDim.x + threadIdx.x;
  if (p >= PIX) return;
  int ch0 = blockIdx.y * 8;
  int bi = p / PLANE;
  int r  = p % PLANE;
  int h  = r / WOUT;
  int wc = r % WOUT;

  float px[27];
  const float* xb = x + (size_t)bi * 3 * HIN * WIN;
#pragma unroll
  for (int c = 0; c < 3; ++c)
#pragma unroll
    for (int dy = 0; dy < 3; ++dy)
#pragma unroll
      for (int dx = 0; dx < 3; ++dx)
        px[c * 9 + dy * 3 + dx] =
            xb[c * HIN * WIN + (size_t)(h + dy) * WIN + (wc + dx)];

  uint32_t tofs4 = (uint32_t)(bi * 120 * PLANE + r) * 4u;
  char* outB = (char*)out;
#pragma unroll
  for (int j = 0; j < 8; ++j) {
    float a = conv_atom(px, w + (size_t)(ch0 + j) * 27, b[ch0 + j]);
    *(float*)(outB + (size_t)(ch0 + j) * PLANE * 4 + tofs4) = a;  // raw act
  }
}

// ======================= phase 2: selection, 1 pixel/thread ================
// Reads raw act back from out (bit-exact), runs gate -> top-k -> keep for all
// four levels in registers, overwrites out. Peak live ~105 VGPR (<128).
__global__ __launch_bounds__(256, 4)
void select_phase(float* __restrict__ out) {
  int p = blockIdx.x * blockDim.x + threadIdx.x;
  if (p >= PIX) return;
  int bi = p / PLANE;
  int r  = p % PLANE;
  uint32_t tofs4 = (uint32_t)(bi * 120 * PLANE + r) * 4u;
  char* outB = (char*)out;

  // Batch-issue the level 0-2 loads (56 independent, deep vmcnt pipeline).
  float act0[8], act1[16], act2[32];
#pragma unroll
  for (int j = 0; j < 8; ++j)
    act0[j] = *(const float*)(outB + (size_t)(0 + j) * PLANE * 4 + tofs4);
#pragma unroll
  for (int j = 0; j < 16; ++j)
    act1[j] = *(const float*)(outB + (size_t)(8 + j) * PLANE * 4 + tofs4);
#pragma unroll
  for (int j = 0; j < 32; ++j)
    act2[j] = *(const float*)(outB + (size_t)(24 + j) * PLANE * 4 + tofs4);

  // ---- level 0: N=8, K=2 (ungated) ----
  uint32_t v0[8];
#pragma unroll
  for (int i = 0; i < 8; ++i) v0[i] = __float_as_uint(act0[i]) & 0x7fffffffu;
  bsort_desc<8>(v0);
  uint32_t mb0 = v0[1];                    // 2nd largest with multiplicity
  float m0 = __uint_as_float(mb0);
  int base0 = 0;
#pragma unroll
  for (int j = 0; j < 8; ++j) base0 += (fabsf(act0[j]) > m0) ? 1 : 0;
  uint64_t msk0 = keep_store<8>(act0, m0, 2 - base0, outB, tofs4, 0);
  uint32_t allow1 = (uint32_t)spread_pairs(msk0, 16);

  // ---- level 1: N=16, K=4 ----
#pragma unroll
  for (int j = 0; j < 16; ++j)
    act1[j] = ((allow1 >> j) & 1u) ? act1[j] : 0.0f;
  uint32_t v1[16];
#pragma unroll
  for (int i = 0; i < 16; ++i) v1[i] = __float_as_uint(act1[i]) & 0x7fffffffu;
  bsort_desc<16>(v1);
  uint32_t mb1 = v1[3];                    // 4th largest with multiplicity
  float m1 = __uint_as_float(mb1);
  int q1 = 0;
#pragma unroll
  for (int i = 0; i < 4; ++i) q1 += (v1[i] == mb1) ? 1 : 0;
  uint64_t msk1 = keep_store<16>(act1, m1, q1, outB, tofs4, 8);
  uint32_t allow2 = (uint32_t)spread_pairs(msk1, 32);

  // ---- level 2: N=32, K=8 ----
#pragma unroll
  for (int j = 0; j < 32; ++j)
    act2[j] = ((allow2 >> j) & 1u) ? act2[j] : 0.0f;
  {
    uint32_t run[16], tmp[16];
#pragma unroll
    for (int i = 0; i < 16; ++i)
      run[i] = __float_as_uint(act2[i]) & 0x7fffffffu;
#pragma unroll
    for (int i = 0; i < 16; ++i)
      tmp[i] = __float_as_uint(act2[16 + i]) & 0x7fffffffu;
    bsort_desc<16>(run);
    bsort_desc<16>(tmp);
#pragma unroll
    for (int i = 0; i < 16; ++i) {        // top-16 of the two desc runs
      uint32_t c = tmp[15 - i];
      run[i] = run[i] > c ? run[i] : c;
    }
    bmerge16(run);                         // fully sorted top-16
    uint32_t mb2 = run[7];                 // 8th largest with multiplicity
    float m2 = __uint_as_float(mb2);
    int q2 = 0;
#pragma unroll
    for (int i = 0; i < 8; ++i) q2 += (run[i] == mb2) ? 1 : 0;
    uint64_t msk2 = keep_store<32>(act2, m2, q2, outB, tofs4, 24);
    uint64_t allow3 = spread_pairs(msk2, 64);

    // ---- level 3: N=64, K=16 ----
    float act3[64];
#pragma unroll
    for (int j = 0; j < 64; ++j)
      act3[j] = *(const float*)(outB + (size_t)(56 + j) * PLANE * 4 + tofs4);
#pragma unroll
    for (int j = 0; j < 64; ++j)
      act3[j] = ((allow3 >> j) & 1ull) ? act3[j] : 0.0f;

    uint32_t r3[16];
#pragma unroll
    for (int i = 0; i < 16; ++i)
      r3[i] = __float_as_uint(act3[i]) & 0x7fffffffu;
    bsort_desc<16>(r3);
#pragma unroll
    for (int g = 1; g < 4; ++g) {
      uint32_t t3[16];
#pragma unroll
      for (int i = 0; i < 16; ++i)
        t3[i] = __float_as_uint(act3[g * 16 + i]) & 0x7fffffffu;
      bsort_desc<16>(t3);
#pragma unroll
      for (int i = 0; i < 16; ++i) {
        uint32_t c = t3[15 - i];
        r3[i] = r3[i] > c ? r3[i] : c;
      }
      if (g < 3) bmerge16(r3);             // keep sorted for next merge only
    }
    uint32_t mb3 = r3[0];                  // min of (unsorted) top-16 multiset
#pragma unroll
    for (int i = 1; i < 16; ++i) mb3 = mb3 < r3[i] ? mb3 : r3[i];
    float m3 = __uint_as_float(mb3);
    int q3 = 0;
#pragma unroll
    for (int i = 0; i < 16; ++i) q3 += (r3[i] == mb3) ? 1 : 0;

    (void)keep_store<64>(act3, m3, q3, outB, tofs4, 56);
  }
}

extern "C" void kernel_launch(void* const* d_in, const int* in_sizes, int n_in,
                              void* d_out, int out_size, void* d_ws, size_t ws_size,
                              hipStream_t stream) {
  const float* x = (const float*)d_in[0];
  const float* w = (const float*)d_in[1];
  const float* b = (const float*)d_in[2];
  float* out = (float*)d_out;

  dim3 blk(256);
  dim3 g1((PIX + 255) / 256, 15);   // 15 channel octets
  dim3 g2((PIX + 255) / 256);
  conv_phase<<<g1, blk, 0, stream>>>(x, w, b, out);
  select_phase<<<g2, blk, 0, stream>>>(out);
}

// Round 12
// 317.723 us; speedup vs baseline: 1.7554x; 1.7554x over previous
//
#include <hip/hip_runtime.h>
#include <stdint.h>

static constexpr int HIN = 256, WIN = 256, HO = 254, WOUT = 254, NB = 8;
static constexpr int PLANE = HO * WOUT;       // 64516
static constexpr int PIX = NB * PLANE;        // 516128

typedef float f32x4 __attribute__((ext_vector_type(4)));

// Per-level atom counts N = {8,16,32,64}, K = {2,4,8,16}, ch0 = {0,8,24,56}.
// Unified tables padded to 64 atoms/level (zeros beyond N): one rolled level
// loop => the whole kernel body is emitted ONCE and stays I-cache resident.
// Padded atoms compute exactly 0.0f; their stores land on higher-level
// channels that this same thread overwrites later (harmless).
// 16B-aligned so weight rows can be read as f32x4 per-lane global loads
// (identical address across lanes -> L1 broadcast; 27.6 KB is L1-resident).
__device__ __align__(16) float g_wPad[4 * 27 * 64];
__device__ float g_bPad[4 * 64];

__constant__ int cN[4]   = {8, 16, 32, 64};
__constant__ int cK[4]   = {2, 4, 8, 16};
__constant__ int cCH0[4] = {0, 8, 24, 56};

// g_wPad[L][s][j] = w[(ch0_L+j)*27 + t(s)] for j<N_L else 0, where step
// s = ky*9+kx*3+c enumerates the VALIDATED (ky,kx,c) FMA order and
// t(s) = c*9+ky*3+kx is the source (c,ky,kx) layout offset.
__global__ void wprep(const float* __restrict__ w, const float* __restrict__ b) {
  int i = blockIdx.x * blockDim.x + threadIdx.x;
  if (i < 4 * 64) {
    int L = i / 64, j = i % 64;
    int N = 8 << L;
    int ch0 = (L == 0) ? 0 : (L == 1) ? 8 : (L == 2) ? 24 : 56;
    g_bPad[i] = (j < N) ? b[ch0 + j] : 0.0f;
  }
  if (i >= 4 * 27 * 64) return;
  int L = i / (27 * 64), r = i % (27 * 64), s = r / 64, j = r % 64;
  int N = 8 << L;
  int ch0 = (L == 0) ? 0 : (L == 1) ? 8 : (L == 2) ? 24 : 56;
  int ky = s / 9, kx = (s / 3) % 3, c = s % 3;
  g_wPad[i] = (j < N) ? w[(size_t)(ch0 + j) * 27 + c * 9 + ky * 3 + kx] : 0.0f;
}

// Ring connectivity: prev atom j feeds next atoms (2j..2j+3) mod a_next.
__device__ __forceinline__ uint64_t spread_pairs(uint64_t mask, int a_next) {
  uint64_t s = mask;
  s = (s | (s << 16)) & 0x0000FFFF0000FFFFull;
  s = (s | (s << 8))  & 0x00FF00FF00FF00FFull;
  s = (s | (s << 4))  & 0x0F0F0F0F0F0F0F0Full;
  s = (s | (s << 2))  & 0x3333333333333333ull;
  s = (s | (s << 1))  & 0x5555555555555555ull;
  uint64_t pair = s | (s << 1);
  uint64_t lim = (a_next >= 64) ? ~0ull : ((1ull << a_next) - 1ull);
  uint64_t rot = ((pair << 2) | (pair >> (a_next - 2))) & lim;
  return (pair | rot) & lim;
}

// Bitonic sort (descending) of 16 uint32 in registers; fully unrolled, static
// indices, pure v_min_u32/v_max_u32.
__device__ __forceinline__ void bsort16(uint32_t (&v)[16]) {
#pragma unroll
  for (int sz = 2; sz <= 16; sz <<= 1) {
#pragma unroll
    for (int st = sz >> 1; st > 0; st >>= 1) {
#pragma unroll
      for (int i = 0; i < 16; ++i) {
        int l = i ^ st;
        if (l > i) {
          uint32_t a = v[i], c = v[l];
          uint32_t mx = a > c ? a : c;
          uint32_t mn = a > c ? c : a;
          bool desc = ((i & sz) == 0);
          v[i] = desc ? mx : mn;
          v[l] = desc ? mn : mx;
        }
      }
    }
  }
}

__device__ __forceinline__ void bmerge16(uint32_t (&v)[16]) {
#pragma unroll
  for (int st = 8; st > 0; st >>= 1) {
#pragma unroll
    for (int i = 0; i < 16; ++i) {
      int l = i ^ st;
      if (l > i) {
        uint32_t a = v[i], c = v[l];
        v[i] = a > c ? a : c;
        v[l] = a > c ? c : a;
      }
    }
  }
}

// Conv numerics (validated): per atom, single f32 accumulator from 0,
// sequential __fmaf_rn in (ky,kx,c) step order (g3*9+ss ascending == the same
// chain), bias added last as a separate __fadd_rn. Selection: jax top_k
// semantics — exactly K kept, boundary ties broken toward LOWEST channel
// index; run[] = sorted top-16 multiset of |act|, m = run[K-1], quota =
// #{i<K: run[i]==m}. Padded atoms (act==0) can only consume quota AFTER all
// real atoms and only when m==0; their stores hit later-level channels that
// this thread overwrites afterward — harmless, so no per-element guard.
//
// __launch_bounds__(128, 3): VGPR cap ~168 (vs 128 at min-waves=4). The
// round 1-11 kernels all reported VGPR_Count=64 => allocator split
// 64 arch + 64 AGPR with v_accvgpr shuttles for the ~160-reg live set.
// Cap 168 lets the whole live set sit in arch VGPRs. 3 waves/SIMD =
// 12 waves/CU ~ the occupancy we actually achieved before.
__global__ __launch_bounds__(128, 3)
void hrtk_main(const float* __restrict__ x, float* __restrict__ out) {
  __shared__ float smem[128 * 27];   // 13824 B/block
  int p = blockIdx.x * blockDim.x + threadIdx.x;
  if (p >= PIX) return;
  int bi = p / PLANE;
  int r  = p % PLANE;
  int h  = r / WOUT;
  int wc = r % WOUT;

  // Stage the 3x3x3 patch into LDS in step order s = ky*9+kx*3+c (value from
  // source (c,ky,kx)) — matches g_wPad's step enumeration exactly.
  // Per-thread row, stride 27 words (odd) -> exactly 2 lanes/bank (free).
  float* pxl = &smem[threadIdx.x * 27];
  const float* xb = x + (size_t)bi * 3 * HIN * WIN;
#pragma unroll
  for (int ky = 0; ky < 3; ++ky)
#pragma unroll
    for (int kx = 0; kx < 3; ++kx)
#pragma unroll
      for (int c = 0; c < 3; ++c)
        pxl[ky * 9 + kx * 3 + c] =
            xb[c * HIN * WIN + (size_t)(h + ky) * WIN + (wc + kx)];

  // Per-thread 32-bit BYTE offset within out; per-channel base is uniform ->
  // global_store saddr form (SGPR base + 32-bit voffset), no per-store VALU.
  uint32_t tofs4 = (uint32_t)(bi * 120 * PLANE + r) * 4u;
  char* outB = (char*)out;
  uint64_t allow = ~0ull;   // level 0 ungated

#pragma unroll 1
  for (int lvl = 0; lvl < 4; ++lvl) {
    const int N = cN[lvl], K = cK[lvl], ch0 = cCH0[lvl];
    const float* wL = g_wPad + lvl * 27 * 64;
    const float* bL = g_bPad + lvl * 64;

    float act[64];
#pragma unroll
    for (int q = 0; q < 4; ++q)
      if (q * 16 < N) {
#pragma unroll
        for (int i = 0; i < 16; ++i) act[q * 16 + i] = 0.0f;
      }

    // ---- conv: 3 rolled s-groups of 9; pw[9] batch-read from LDS (deep ds
    // prefetch); weights as per-lane f32x4 GLOBAL loads (L1-broadcast, deep
    // vmcnt pipelining) ----
#pragma unroll 1
    for (int g3 = 0; g3 < 3; ++g3) {
      const float* pg = pxl + g3 * 9;
      float pw[9];
#pragma unroll
      for (int ss = 0; ss < 9; ++ss) pw[ss] = pg[ss];
      const float* wg = wL + g3 * 9 * 64;
#pragma unroll
      for (int q = 0; q < 4; ++q)
        if (q * 16 < N) {
#pragma unroll
          for (int ss = 0; ss < 9; ++ss) {
            const f32x4* wr = (const f32x4*)(wg + ss * 64 + q * 16);
            f32x4 w0 = wr[0], w1 = wr[1], w2 = wr[2], w3 = wr[3];
#pragma unroll
            for (int i = 0; i < 4; ++i) {
              act[q * 16 + 0  + i] = __fmaf_rn(pw[ss], w0[i], act[q * 16 + 0  + i]);
              act[q * 16 + 4  + i] = __fmaf_rn(pw[ss], w1[i], act[q * 16 + 4  + i]);
              act[q * 16 + 8  + i] = __fmaf_rn(pw[ss], w2[i], act[q * 16 + 8  + i]);
              act[q * 16 + 12 + i] = __fmaf_rn(pw[ss], w3[i], act[q * 16 + 12 + i]);
            }
          }
        }
    }

    // ---- bias + gate ----
#pragma unroll
    for (int q = 0; q < 4; ++q)
      if (q * 16 < N) {
#pragma unroll
        for (int i = 0; i < 16; ++i) {
          int j = q * 16 + i;
          float a = __fadd_rn(act[j], bL[j]);          // bias after conv
          act[j] = ((allow >> j) & 1ull) ? a : 0.0f;
        }
      }

    // ---- selection: sorted top-16 via grouped bitonic ----
    uint32_t run[16];
#pragma unroll
    for (int i = 0; i < 16; ++i)
      run[i] = __float_as_uint(act[i]) & 0x7fffffffu;
    bsort16(run);
#pragma unroll
    for (int g = 1; g < 4; ++g) {
      if (g * 16 < N) {
        uint32_t tmp[16];
#pragma unroll
        for (int i = 0; i < 16; ++i)
          tmp[i] = __float_as_uint(act[g * 16 + i]) & 0x7fffffffu;
        bsort16(tmp);
#pragma unroll
        for (int i = 0; i < 16; ++i) {   // keep top-16 of the two desc runs
          uint32_t c = tmp[15 - i];
          run[i] = run[i] > c ? run[i] : c;
        }
        bmerge16(run);                   // re-sort (run stays fully sorted)
      }
    }

    uint32_t mb = 0;                     // m = run[K-1], K runtime uniform
#pragma unroll
    for (int i = 0; i < 16; ++i) mb = (i == K - 1) ? run[i] : mb;
    float m = __uint_as_float(mb);
    int quota = 0;                       // #{i<K: run[i]==m}
#pragma unroll
    for (int i = 0; i < 16; ++i) quota += (i < K && run[i] == mb) ? 1 : 0;

    // ---- keep + store + mask (quarter-guarded; padded j harmless).
    // Store: uniform SGPR base per channel + tofs4 voffset (saddr form). ----
    uint64_t msk = 0;
#pragma unroll
    for (int q = 0; q < 4; ++q)
      if (q * 16 < N) {
#pragma unroll
        for (int i = 0; i < 16; ++i) {
          int j = q * 16 + i;
          float aj = fabsf(act[j]);
          bool eq = (aj == m);
          bool keep = (aj > m) || (eq && quota > 0);
          quota -= eq ? 1 : 0;
          float v = keep ? act[j] : 0.0f;
          *(float*)(outB + (size_t)(ch0 + j) * PLANE * 4 + tofs4) = v;
          msk |= (v != 0.0f) ? (1ull << j) : 0ull;
        }
      }

    if (lvl < 3) allow = spread_pairs(msk, cN[lvl + 1]);
  }
}

extern "C" void kernel_launch(void* const* d_in, const int* in_sizes, int n_in,
                              void* d_out, int out_size, void* d_ws, size_t ws_size,
                              hipStream_t stream) {
  const float* x = (const float*)d_in[0];
  const float* w = (const float*)d_in[1];
  const float* b = (const float*)d_in[2];
  float* out = (float*)d_out;

  wprep<<<dim3((4 * 27 * 64 + 255) / 256), dim3(256), 0, stream>>>(w, b);
  dim3 blk(128), grid((PIX + 127) / 128);
  hrtk_main<<<grid, blk, 0, stream>>>(x, out);
}